// Round 2
// baseline (1951.385 us; speedup 1.0000x reference)
//
#include <hip/hip_runtime.h>
#include <hip/hip_fp16.h>
#include <cstdint>
#include <cstddef>

// Problem constants (setup_inputs: B=8,S=2048,D=768,E=8,I=3072,H=1536,top_k=2)
#define TK 16384   // tokens
#define DD 768
#define EE 8
#define II 3072
#define HH 1536

typedef _Float16 half8 __attribute__((ext_vector_type(8)));
typedef float floatx4 __attribute__((ext_vector_type(4)));

typedef const __attribute__((address_space(1))) uint32_t* gptr_t;
typedef __attribute__((address_space(3))) uint32_t* lptr_t;

#define GLOAD_LDS16(gp, lp) __builtin_amdgcn_global_load_lds( \
    (gptr_t)(const void*)(gp), (lptr_t)(void*)(lp), 16, 0, 0)

// ---------------- fp32 -> fp16 convert (vectorized) ----------------
__global__ void cvt_kernel(const float* __restrict__ in, __half* __restrict__ out, long n) {
  long i = (long)blockIdx.x * blockDim.x + threadIdx.x;
  long stride = (long)gridDim.x * blockDim.x;
  for (long j = i * 4; j < n; j += stride * 4) {
    float4 v = *(const float4*)(in + j);
    __half2 a = __floats2half2_rn(v.x, v.y);
    __half2 b = __floats2half2_rn(v.z, v.w);
    uint2 p;
    p.x = *(const unsigned int*)&a;
    p.y = *(const unsigned int*)&b;
    *(uint2*)(out + j) = p;
  }
}

// ------- fp32 [E][K][N] -> fp16 [E][N][K] transpose-convert -------
__global__ void cvtT_kernel(const float* __restrict__ in, __half* __restrict__ out,
                            int K, int N) {
  __shared__ float tile[32][33];
  int e = blockIdx.z;
  const float* inp = in + (size_t)e * K * N;
  __half* outp = out + (size_t)e * K * N;
  int n0 = blockIdx.x * 32, k0 = blockIdx.y * 32;
  int tx = threadIdx.x, ty = threadIdx.y;
#pragma unroll
  for (int i = 0; i < 4; ++i)
    tile[ty + i * 8][tx] = inp[(size_t)(k0 + ty + i * 8) * N + n0 + tx];
  __syncthreads();
#pragma unroll
  for (int i = 0; i < 4; ++i)
    outp[(size_t)(n0 + ty + i * 8) * K + k0 + tx] = __float2half(tile[tx][ty + i * 8]);
}

// ---------------- router: fp32 logits, top-2, softmax ----------------
__global__ __launch_bounds__(256)
void router_kernel(const float* __restrict__ x, const float* __restrict__ Wr,
                   const float* __restrict__ br, int* __restrict__ counts,
                   int* __restrict__ sel, float* __restrict__ wTok) {
  __shared__ float wr_s[EE * DD];  // transposed [e][d], 24KB
  for (int i = threadIdx.x; i < EE * DD; i += 256) {
    int d = i >> 3, e = i & 7;
    wr_s[e * DD + d] = Wr[i];
  }
  __syncthreads();
  int wid = threadIdx.x >> 6, lane = threadIdx.x & 63;
  int t = blockIdx.x * 4 + wid;
  const float* xt = x + (size_t)t * DD;
  float acc[EE];
#pragma unroll
  for (int e = 0; e < EE; ++e) acc[e] = 0.f;
  for (int d = lane; d < DD; d += 64) {
    float xv = xt[d];
#pragma unroll
    for (int e = 0; e < EE; ++e) acc[e] += xv * wr_s[e * DD + d];
  }
#pragma unroll
  for (int off = 32; off > 0; off >>= 1)
#pragma unroll
    for (int e = 0; e < EE; ++e) acc[e] += __shfl_xor(acc[e], off);
  if (lane == 0) {
    float v[EE];
#pragma unroll
    for (int e = 0; e < EE; ++e) v[e] = acc[e] + br[e];
    int i0 = 0;
#pragma unroll
    for (int e = 1; e < EE; ++e) if (v[e] > v[i0]) i0 = e;
    int i1 = (i0 == 0) ? 1 : 0;
#pragma unroll
    for (int e = 0; e < EE; ++e) if (e != i0 && v[e] > v[i1] && e != i1) { if (v[e] > v[i1]) i1 = e; }
    float e1 = __expf(v[i1] - v[i0]);
    float s = 1.f / (1.f + e1);
    sel[2 * t] = i0; sel[2 * t + 1] = i1;
    wTok[2 * t] = s; wTok[2 * t + 1] = e1 * s;
    atomicAdd(&counts[i0], 1);
    atomicAdd(&counts[i1], 1);
  }
}

// ---------------- offsets (prefix over 8) ----------------
__global__ void offsets_kernel(const int* __restrict__ counts, int* __restrict__ offsets,
                               int* __restrict__ cursors) {
  if (threadIdx.x == 0) {
    int o = 0;
    for (int e = 0; e < EE; ++e) { offsets[e] = o; cursors[e] = o; o += counts[e]; }
  }
}

// ---------------- scatter token->slot ----------------
__global__ void scatter_kernel(const int* __restrict__ sel, int* __restrict__ cursors,
                               int* __restrict__ idxList, int* __restrict__ posTok) {
  int t = blockIdx.x * 256 + threadIdx.x;
  if (t < TK) {
#pragma unroll
    for (int k = 0; k < 2; ++k) {
      int e = sel[2 * t + k];
      int p = atomicAdd(&cursors[e], 1);
      idxList[p] = t;
      posTok[2 * t + k] = p;
    }
  }
}

// ---------------- FFN GEMM: 256x256 tile, BK=64, 8 waves (2Mx4N), 8-phase ----------------
// Wt layout: [E][N][K] (pre-transposed). XOR-swizzled LDS (pre-swizzled global source).
// Staging granularity: 64-row quarters (1 global_load_lds per thread each).
// Schedule (tile t, 4 phases a-d):
//   a: ds Q0 (12xb128) | stage B-q2,q3(t+1) -> buf^1   [retired at (t-1).b]
//   b: ds Q1 (4)       | stage A-q0,q2(t+2) -> buf     [retired at t.a]
//   c: ds Q2 (8)       | stage B-q0,q1(t+2) -> buf     [retired at t.b]
//   d: -               | stage A-q1,q3(t+2) -> buf     [retired at t.c]
//      then vmcnt(6) (3 quarter-stages in flight) -> tile t+1 fully landed.
//   When t+2 >= NT the b/c/d stages are skipped -> must drain vmcnt(0) instead.
template<int KD, int ND, bool GATHER, bool GELU>
__global__ __launch_bounds__(512, 2)
void ffn_gemm(const __half* __restrict__ A, const __half* __restrict__ Wt,
              const float* __restrict__ Bias, __half* __restrict__ Out,
              const int* __restrict__ counts, const int* __restrict__ offsets,
              const int* __restrict__ idxList) {
  constexpr int NT = KD / 64;
  const int e = blockIdx.z;
  const int cnt = counts[e];
  const int m0 = blockIdx.x * 256;          // M fastest: consecutive blocks share B-panel
  if (cnt == 0 || m0 >= cnt) return;
  const int off = offsets[e];
  const int n0 = blockIdx.y * 256;
  const __half* We = Wt + (size_t)e * KD * ND;
  const float* be = Bias + (size_t)e * ND;

  __shared__ __align__(16) __half As[2][256 * 64];
  __shared__ __align__(16) __half Bs[2][256 * 64];

  const int tid = threadIdx.x;
  const int srow = tid >> 3;                 // 0..63 row within quarter
  const int swz = ((tid & 7) ^ (srow & 7)) << 3;  // pre-swizzled source column (halfs)

  const __half* aptr[4];
  const __half* bptr[4];
#pragma unroll
  for (int q = 0; q < 4; ++q) {
    int gr = m0 + q * 64 + srow;
    if (gr > cnt - 1) gr = cnt - 1;          // clamp tail (writes guarded)
    size_t arow = GATHER ? (size_t)idxList[off + gr] : (size_t)(off + gr);
    aptr[q] = A + arow * KD + swz;
    bptr[q] = We + (size_t)(n0 + q * 64 + srow) * KD + swz;
  }

#define STAGE_A(BUF, Q, TS) GLOAD_LDS16(aptr[Q] + (TS) * 64, &As[BUF][(Q) * 4096 + tid * 8])
#define STAGE_B(BUF, Q, TS) GLOAD_LDS16(bptr[Q] + (TS) * 64, &Bs[BUF][(Q) * 4096 + tid * 8])

  const int lane = tid & 63, wv = tid >> 6;
  const int wr = wv >> 2, wc = wv & 3;       // 2 x 4 wave grid
  const int lrow = lane & 15, lg = lane >> 4;
  const int rowa = wr * 128 + lrow;
  const int rowb = wc * 64 + lrow;
  int aoff[2], boff[2];
#pragma unroll
  for (int kk = 0; kk < 2; ++kk) {
    aoff[kk] = rowa * 64 + (((kk * 4 + lg) ^ (rowa & 7)) << 3);
    boff[kk] = rowb * 64 + (((kk * 4 + lg) ^ (rowb & 7)) << 3);
  }

  floatx4 acc[8][4];
#pragma unroll
  for (int mi = 0; mi < 8; ++mi)
#pragma unroll
    for (int ni = 0; ni < 4; ++ni) acc[mi][ni] = (floatx4){0.f, 0.f, 0.f, 0.f};

  // ---- prologue: tile0 fully, tile1 minus B-q2,q3 (staged at t0.a) ----
#pragma unroll
  for (int q = 0; q < 4; ++q) STAGE_A(0, q, 0);
#pragma unroll
  for (int q = 0; q < 4; ++q) STAGE_B(0, q, 0);
#pragma unroll
  for (int q = 0; q < 4; ++q) STAGE_A(1, q, 1);
  STAGE_B(1, 0, 1);
  STAGE_B(1, 1, 1);
  asm volatile("s_waitcnt vmcnt(6)" ::: "memory");   // tile0's 8 quarters landed
  __builtin_amdgcn_s_barrier();

#define BAR() __builtin_amdgcn_s_barrier()
#define WLG() do { asm volatile("s_waitcnt lgkmcnt(0)" ::: "memory"); \
                   __builtin_amdgcn_sched_barrier(0); } while (0)
#define P1() __builtin_amdgcn_s_setprio(1)
#define P0() __builtin_amdgcn_s_setprio(0)
#define MMQ(AF, BF, MB, NB) \
  _Pragma("unroll") for (int kk = 0; kk < 2; ++kk) \
  _Pragma("unroll") for (int mi = 0; mi < 4; ++mi) \
  _Pragma("unroll") for (int ni = 0; ni < 2; ++ni) \
    acc[(MB) + mi][(NB) + ni] = __builtin_amdgcn_mfma_f32_16x16x32_f16( \
        AF[mi][kk], BF[ni][kk], acc[(MB) + mi][(NB) + ni], 0, 0, 0);

#define PHASES(CUR, NXT, TT) { \
  const __half* Ac = &As[CUR][0]; \
  const __half* Bc = &Bs[CUR][0]; \
  half8 af[4][2], bf0[2][2], bf1[2][2]; \
  _Pragma("unroll") for (int mi = 0; mi < 4; ++mi) \
  _Pragma("unroll") for (int kk = 0; kk < 2; ++kk) \
    af[mi][kk] = *(const half8*)&Ac[aoff[kk] + mi * 1024]; \
  _Pragma("unroll") for (int ni = 0; ni < 2; ++ni) \
  _Pragma("unroll") for (int kk = 0; kk < 2; ++kk) \
    bf0[ni][kk] = *(const half8*)&Bc[boff[kk] + ni * 1024]; \
  if ((TT) + 1 < NT) { STAGE_B(NXT, 2, (TT) + 1); STAGE_B(NXT, 3, (TT) + 1); } \
  BAR(); WLG(); P1(); MMQ(af, bf0, 0, 0); P0(); BAR(); \
  _Pragma("unroll") for (int ni = 0; ni < 2; ++ni) \
  _Pragma("unroll") for (int kk = 0; kk < 2; ++kk) \
    bf1[ni][kk] = *(const half8*)&Bc[boff[kk] + (ni + 2) * 1024]; \
  if ((TT) + 2 < NT) { STAGE_A(CUR, 0, (TT) + 2); STAGE_A(CUR, 2, (TT) + 2); } \
  BAR(); WLG(); P1(); MMQ(af, bf1, 0, 2); P0(); BAR(); \
  _Pragma("unroll") for (int mi = 0; mi < 4; ++mi) \
  _Pragma("unroll") for (int kk = 0; kk < 2; ++kk) \
    af[mi][kk] = *(const half8*)&Ac[aoff[kk] + (mi + 4) * 1024]; \
  if ((TT) + 2 < NT) { STAGE_B(CUR, 0, (TT) + 2); STAGE_B(CUR, 1, (TT) + 2); } \
  BAR(); WLG(); P1(); MMQ(af, bf0, 4, 0); P0(); BAR(); \
  if ((TT) + 2 < NT) { STAGE_A(CUR, 1, (TT) + 2); STAGE_A(CUR, 3, (TT) + 2); } \
  BAR(); P1(); MMQ(af, bf1, 4, 2); P0(); \
  if ((TT) + 2 < NT) { asm volatile("s_waitcnt vmcnt(6)" ::: "memory"); } \
  else              { asm volatile("s_waitcnt vmcnt(0)" ::: "memory"); } \
  BAR(); }

  for (int t = 0; t < NT; t += 2) {
    PHASES(0, 1, t)
    PHASES(1, 0, t + 1)
  }

  // ---- epilogue: bias + optional erf-GELU, guarded rows ----
  const int crow = m0 + wr * 128 + lg * 4;
  const int ccol = n0 + wc * 64 + lrow;
  float bv[4];
#pragma unroll
  for (int ni = 0; ni < 4; ++ni) bv[ni] = be[ccol + ni * 16];
#pragma unroll
  for (int mi = 0; mi < 8; ++mi) {
#pragma unroll
    for (int j = 0; j < 4; ++j) {
      int r = crow + mi * 16 + j;
      if (r < cnt) {
#pragma unroll
        for (int ni = 0; ni < 4; ++ni) {
          float v = acc[mi][ni][j] + bv[ni];
          if (GELU) v = 0.5f * v * (1.f + erff(v * 0.70710678118654752f));
          Out[(size_t)(off + r) * ND + ccol + ni * 16] = __float2half(v);
        }
      }
    }
  }
#undef STAGE_A
#undef STAGE_B
#undef BAR
#undef WLG
#undef P1
#undef P0
#undef MMQ
#undef PHASES
}

// ---------------- combine: out[t] = w0*yc[p0] + w1*yc[p1] ----------------
__global__ void combine_kernel(const __half* __restrict__ yc, const float* __restrict__ wTok,
                               const int* __restrict__ posTok, float* __restrict__ out) {
  int t = blockIdx.x;
  int d = threadIdx.x * 4;
  if (d >= DD) return;
  float w0 = wTok[2 * t], w1 = wTok[2 * t + 1];
  const __half2* a = (const __half2*)(yc + (size_t)posTok[2 * t] * DD + d);
  const __half2* b = (const __half2*)(yc + (size_t)posTok[2 * t + 1] * DD + d);
  float2 a0 = __half22float2(a[0]), a1 = __half22float2(a[1]);
  float2 b0 = __half22float2(b[0]), b1 = __half22float2(b[1]);
  float4 r;
  r.x = w0 * a0.x + w1 * b0.x;
  r.y = w0 * a0.y + w1 * b0.y;
  r.z = w0 * a1.x + w1 * b1.x;
  r.w = w0 * a1.y + w1 * b1.y;
  *(float4*)(out + (size_t)t * DD + d) = r;
}

extern "C" void kernel_launch(void* const* d_in, const int* in_sizes, int n_in,
                              void* d_out, int out_size, void* d_ws, size_t ws_size,
                              hipStream_t stream) {
  const float* x  = (const float*)d_in[0];
  const float* Wr = (const float*)d_in[1];
  const float* br = (const float*)d_in[2];
  const float* W1 = (const float*)d_in[3];
  const float* b1 = (const float*)d_in[4];
  const float* W2 = (const float*)d_in[5];
  const float* b2 = (const float*)d_in[6];
  const float* W3 = (const float*)d_in[7];
  const float* b3 = (const float*)d_in[8];
  float* out = (float*)d_out;

  char* ws = (char*)d_ws;
  size_t o = 0;
  auto alloc = [&](size_t bytes) {
    char* p = ws + o;
    o += (bytes + 255) & ~(size_t)255;
    return p;
  };
  __half* xh   = (__half*)alloc((size_t)TK * DD * 2);
  __half* w1t  = (__half*)alloc((size_t)EE * DD * II * 2);
  __half* w2t  = (__half*)alloc((size_t)EE * II * HH * 2);
  __half* w3t  = (__half*)alloc((size_t)EE * HH * DD * 2);
  __half* h1   = (__half*)alloc((size_t)2 * TK * II * 2);
  __half* h2   = (__half*)alloc((size_t)2 * TK * HH * 2);
  __half* yc   = (__half*)alloc((size_t)2 * TK * DD * 2);
  int*   idxL  = (int*)alloc(2 * TK * 4);
  int*   sel   = (int*)alloc(2 * TK * 4);
  float* wTok  = (float*)alloc(2 * TK * 4);
  int*   posT  = (int*)alloc(2 * TK * 4);
  int*   counts  = (int*)alloc(256);
  int*   offsets = (int*)alloc(256);
  int*   cursors = (int*)alloc(256);
  if (o > ws_size) return;  // workspace too small -> loud absmax failure

  hipMemsetAsync(counts, 0, 256, stream);

  cvt_kernel<<<2048, 256, 0, stream>>>(x, xh, (long)TK * DD);
  cvtT_kernel<<<dim3(II / 32, DD / 32, EE), dim3(32, 8), 0, stream>>>(W1, w1t, DD, II);
  cvtT_kernel<<<dim3(HH / 32, II / 32, EE), dim3(32, 8), 0, stream>>>(W2, w2t, II, HH);
  cvtT_kernel<<<dim3(DD / 32, HH / 32, EE), dim3(32, 8), 0, stream>>>(W3, w3t, HH, DD);
  router_kernel<<<TK / 4, 256, 0, stream>>>(x, Wr, br, counts, sel, wTok);
  offsets_kernel<<<1, 64, 0, stream>>>(counts, offsets, cursors);
  scatter_kernel<<<TK / 256, 256, 0, stream>>>(sel, cursors, idxL, posT);

  ffn_gemm<DD, II, true,  true ><<<dim3(64, II / 256, EE), 512, 0, stream>>>(
      xh, w1t, b1, h1, counts, offsets, idxL);
  ffn_gemm<II, HH, false, true ><<<dim3(64, HH / 256, EE), 512, 0, stream>>>(
      h1, w2t, b2, h2, counts, offsets, idxL);
  ffn_gemm<HH, DD, false, false><<<dim3(64, DD / 256, EE), 512, 0, stream>>>(
      h2, w3t, b3, yc, counts, offsets, idxL);

  combine_kernel<<<TK, 192, 0, stream>>>(yc, wTok, posT, out);
}

// Round 3
// 1687.226 us; speedup vs baseline: 1.1566x; 1.1566x over previous
//
#include <hip/hip_runtime.h>
#include <hip/hip_fp16.h>
#include <cstdint>
#include <cstddef>

// Problem constants (setup_inputs: B=8,S=2048,D=768,E=8,I=3072,H=1536,top_k=2)
#define TK 16384   // tokens
#define DD 768
#define EE 8
#define II 3072
#define HH 1536

typedef _Float16 half8 __attribute__((ext_vector_type(8)));
typedef float floatx4 __attribute__((ext_vector_type(4)));

typedef const __attribute__((address_space(1))) uint32_t* gptr_t;
typedef __attribute__((address_space(3))) uint32_t* lptr_t;

#define GLOAD_LDS16(gp, lp) __builtin_amdgcn_global_load_lds( \
    (gptr_t)(const void*)(gp), (lptr_t)(void*)(lp), 16, 0, 0)

// ------- fp32 [E][K][N] -> fp16 [E][N][K] transpose-convert -------
__global__ void cvtT_kernel(const float* __restrict__ in, __half* __restrict__ out,
                            int K, int N) {
  __shared__ float tile[32][33];
  int e = blockIdx.z;
  const float* inp = in + (size_t)e * K * N;
  __half* outp = out + (size_t)e * K * N;
  int n0 = blockIdx.x * 32, k0 = blockIdx.y * 32;
  int tx = threadIdx.x, ty = threadIdx.y;
#pragma unroll
  for (int i = 0; i < 4; ++i)
    tile[ty + i * 8][tx] = inp[(size_t)(k0 + ty + i * 8) * N + n0 + tx];
  __syncthreads();
#pragma unroll
  for (int i = 0; i < 4; ++i)
    outp[(size_t)(n0 + ty + i * 8) * K + k0 + tx] = __float2half(tile[tx][ty + i * 8]);
}

// ------- router: fp32 logits, top-2, softmax; also emits xh (fp16 copy of x) -------
__global__ __launch_bounds__(256)
void router_kernel(const float* __restrict__ x, const float* __restrict__ Wr,
                   const float* __restrict__ br, int* __restrict__ counts,
                   int* __restrict__ sel, float* __restrict__ wTok,
                   __half* __restrict__ xh) {
  __shared__ float wr_s[EE * DD];  // transposed [e][d], 24KB
  for (int i = threadIdx.x; i < EE * DD; i += 256) {
    int d = i >> 3, e = i & 7;
    wr_s[e * DD + d] = Wr[i];
  }
  __syncthreads();
  int wid = threadIdx.x >> 6, lane = threadIdx.x & 63;
  int t = blockIdx.x * 4 + wid;
  const float* xt = x + (size_t)t * DD;
  float acc[EE];
#pragma unroll
  for (int e = 0; e < EE; ++e) acc[e] = 0.f;
  for (int d = lane; d < DD; d += 64) {
    float xv = xt[d];
#pragma unroll
    for (int e = 0; e < EE; ++e) acc[e] += xv * wr_s[e * DD + d];
  }
#pragma unroll
  for (int off = 32; off > 0; off >>= 1)
#pragma unroll
    for (int e = 0; e < EE; ++e) acc[e] += __shfl_xor(acc[e], off);
  if (lane == 0) {
    float v[EE];
#pragma unroll
    for (int e = 0; e < EE; ++e) v[e] = acc[e] + br[e];
    int i0 = 0;
#pragma unroll
    for (int e = 1; e < EE; ++e) if (v[e] > v[i0]) i0 = e;
    int i1 = (i0 == 0) ? 1 : 0;
#pragma unroll
    for (int e = 0; e < EE; ++e) if (e != i0 && v[e] > v[i1] && e != i1) { if (v[e] > v[i1]) i1 = e; }
    float e1 = __expf(v[i1] - v[i0]);
    float s = 1.f / (1.f + e1);
    sel[2 * t] = i0; sel[2 * t + 1] = i1;
    wTok[2 * t] = s; wTok[2 * t + 1] = e1 * s;
    atomicAdd(&counts[i0], 1);
    atomicAdd(&counts[i1], 1);
  }
  // fused x -> fp16 conversion for this wave's token row (replaces cvt_kernel)
  const float4* xr = (const float4*)xt;
  uint2* xo = (uint2*)(xh + (size_t)t * DD);
#pragma unroll
  for (int j = 0; j < 3; ++j) {
    float4 v = xr[lane + j * 64];
    __half2 a = __floats2half2_rn(v.x, v.y);
    __half2 b = __floats2half2_rn(v.z, v.w);
    uint2 p;
    p.x = *(const unsigned int*)&a;
    p.y = *(const unsigned int*)&b;
    xo[lane + j * 64] = p;
  }
}

// ---------------- offsets (prefix over 8) ----------------
__global__ void offsets_kernel(const int* __restrict__ counts, int* __restrict__ offsets,
                               int* __restrict__ cursors) {
  if (threadIdx.x == 0) {
    int o = 0;
    for (int e = 0; e < EE; ++e) { offsets[e] = o; cursors[e] = o; o += counts[e]; }
  }
}

// ---------------- scatter token->slot ----------------
__global__ void scatter_kernel(const int* __restrict__ sel, int* __restrict__ cursors,
                               int* __restrict__ idxList, int* __restrict__ posTok) {
  int t = blockIdx.x * 256 + threadIdx.x;
  if (t < TK) {
#pragma unroll
    for (int k = 0; k < 2; ++k) {
      int e = sel[2 * t + k];
      int p = atomicAdd(&cursors[e], 1);
      idxList[p] = t;
      posTok[2 * t + k] = p;
    }
  }
}

// ---------------- FFN GEMM: C[cnt,N] = A[cnt,K] @ Wt[e] (+bias, gelu) ----------------
// 128x128 tile, BK=64, 4 waves (2x2), 16x16x32 f16 MFMA, XOR-swizzled LDS.
// T3 minimum-2-phase: explicit LDS double buffer; issue STAGE(t+1) BEFORE the
// ds_read+MFMA of tile t; ONE __syncthreads per tile (its vmcnt(0)+lgkm drain
// is the only sync). Staging latency hides under 32 MFMAs; with 64KB LDS two
// blocks co-reside per CU and cover each other's drains.
template<int KD, int ND, bool GATHER, bool GELU>
__global__ __launch_bounds__(256, 2)
void ffn_gemm(const __half* __restrict__ A, const __half* __restrict__ Wt,
              const float* __restrict__ Bias, __half* __restrict__ Out,
              const int* __restrict__ counts, const int* __restrict__ offsets,
              const int* __restrict__ idxList) {
  constexpr int NT = KD / 64;                 // 12 / 48 / 24 — all even
  const int e = blockIdx.z;
  const int cnt = counts[e];
  const int m0 = blockIdx.y * 128;
  if (cnt == 0 || m0 >= cnt) return;
  const int off = offsets[e];
  const int n0 = blockIdx.x * 128;
  const __half* We = Wt + (size_t)e * KD * ND;
  const float* be = Bias + (size_t)e * ND;

  __shared__ __align__(16) __half As[2][128 * 64];
  __shared__ __align__(16) __half Bs[2][128 * 64];

  const int tid = threadIdx.x;

  // staging source addresses: slot s = i*256+tid; row = s/8, scol = s%8
  // global col pre-swizzled: (scol ^ (row&7))*8  (matches swizzled read below)
  const __half* abase[4];
  const __half* bbase[4];
#pragma unroll
  for (int i = 0; i < 4; ++i) {
    int s = i * 256 + tid;
    int row = s >> 3;
    int sc = s & 7;
    int r = m0 + row; if (r > cnt - 1) r = cnt - 1;  // clamp tail (writes guarded)
    size_t arow = GATHER ? (size_t)idxList[off + r] : (size_t)(off + r);
    abase[i] = A + arow * KD + ((sc ^ (row & 7)) << 3);
    bbase[i] = We + (size_t)(n0 + row) * KD + ((sc ^ (row & 7)) << 3);
  }

  floatx4 acc[4][4];
#pragma unroll
  for (int mi = 0; mi < 4; ++mi)
#pragma unroll
    for (int ni = 0; ni < 4; ++ni) acc[mi][ni] = (floatx4){0.f, 0.f, 0.f, 0.f};

  const int lane = tid & 63;
  const int wv = tid >> 6;
  const int wr = wv >> 1, wc = wv & 1;
  const int lrow = lane & 15, lg = lane >> 4;

  int aoff[4][2], boff[4][2];
#pragma unroll
  for (int mi = 0; mi < 4; ++mi) {
    int row = wr * 64 + mi * 16 + lrow;
#pragma unroll
    for (int kk = 0; kk < 2; ++kk) {
      int slot = kk * 4 + lg;
      aoff[mi][kk] = row * 64 + ((slot ^ (row & 7)) << 3);
    }
  }
#pragma unroll
  for (int ni = 0; ni < 4; ++ni) {
    int row = wc * 64 + ni * 16 + lrow;
#pragma unroll
    for (int kk = 0; kk < 2; ++kk) {
      int slot = kk * 4 + lg;
      boff[ni][kk] = row * 64 + ((slot ^ (row & 7)) << 3);
    }
  }

  // ---- prologue: stage tile 0 into buf 0 ----
#pragma unroll
  for (int i = 0; i < 4; ++i) GLOAD_LDS16(abase[i], &As[0][i * 2048 + tid * 8]);
#pragma unroll
  for (int i = 0; i < 4; ++i) GLOAD_LDS16(bbase[i], &Bs[0][i * 2048 + tid * 8]);
  __syncthreads();   // drains vmcnt(0): tile 0 landed

#define TILE(CUR, NXT, TT)                                                    \
  {                                                                           \
    if ((TT) + 1 < NT) {                                                      \
      _Pragma("unroll") for (int i = 0; i < 4; ++i)                           \
        GLOAD_LDS16(abase[i] + ((TT) + 1) * 64, &As[NXT][i * 2048 + tid * 8]);\
      _Pragma("unroll") for (int i = 0; i < 4; ++i)                           \
        GLOAD_LDS16(bbase[i] + ((TT) + 1) * 64, &Bs[NXT][i * 2048 + tid * 8]);\
    }                                                                         \
    _Pragma("unroll") for (int kk = 0; kk < 2; ++kk) {                        \
      half8 af[4], bf[4];                                                     \
      _Pragma("unroll") for (int mi = 0; mi < 4; ++mi)                        \
        af[mi] = *(const half8*)&As[CUR][aoff[mi][kk]];                       \
      _Pragma("unroll") for (int ni = 0; ni < 4; ++ni)                        \
        bf[ni] = *(const half8*)&Bs[CUR][boff[ni][kk]];                       \
      _Pragma("unroll") for (int mi = 0; mi < 4; ++mi)                        \
        _Pragma("unroll") for (int ni = 0; ni < 4; ++ni)                      \
          acc[mi][ni] = __builtin_amdgcn_mfma_f32_16x16x32_f16(               \
              af[mi], bf[ni], acc[mi][ni], 0, 0, 0);                          \
    }                                                                         \
    __syncthreads(); /* vmcnt(0): tile TT+1 landed; all reads of CUR done */  \
  }

  for (int t = 0; t < NT; t += 2) {
    TILE(0, 1, t)
    TILE(1, 0, t + 1)
  }
#undef TILE

  // epilogue: C row = (lane>>4)*4 + j, col = lane&15 per 16x16 fragment
#pragma unroll
  for (int ni = 0; ni < 4; ++ni) {
    int col = n0 + wc * 64 + ni * 16 + lrow;
    float bv = be[col];
#pragma unroll
    for (int mi = 0; mi < 4; ++mi) {
      int rbase = m0 + wr * 64 + mi * 16 + lg * 4;
#pragma unroll
      for (int j = 0; j < 4; ++j) {
        int r = rbase + j;
        if (r < cnt) {
          float v = acc[mi][ni][j] + bv;
          if (GELU) v = 0.5f * v * (1.f + erff(v * 0.70710678118654752f));
          Out[(size_t)(off + r) * ND + col] = __float2half(v);
        }
      }
    }
  }
}

// ---------------- combine: out[t] = w0*yc[p0] + w1*yc[p1] ----------------
__global__ void combine_kernel(const __half* __restrict__ yc, const float* __restrict__ wTok,
                               const int* __restrict__ posTok, float* __restrict__ out) {
  int t = blockIdx.x;
  int d = threadIdx.x * 4;
  if (d >= DD) return;
  float w0 = wTok[2 * t], w1 = wTok[2 * t + 1];
  const __half2* a = (const __half2*)(yc + (size_t)posTok[2 * t] * DD + d);
  const __half2* b = (const __half2*)(yc + (size_t)posTok[2 * t + 1] * DD + d);
  float2 a0 = __half22float2(a[0]), a1 = __half22float2(a[1]);
  float2 b0 = __half22float2(b[0]), b1 = __half22float2(b[1]);
  float4 r;
  r.x = w0 * a0.x + w1 * b0.x;
  r.y = w0 * a0.y + w1 * b0.y;
  r.z = w0 * a1.x + w1 * b1.x;
  r.w = w0 * a1.y + w1 * b1.y;
  *(float4*)(out + (size_t)t * DD + d) = r;
}

extern "C" void kernel_launch(void* const* d_in, const int* in_sizes, int n_in,
                              void* d_out, int out_size, void* d_ws, size_t ws_size,
                              hipStream_t stream) {
  const float* x  = (const float*)d_in[0];
  const float* Wr = (const float*)d_in[1];
  const float* br = (const float*)d_in[2];
  const float* W1 = (const float*)d_in[3];
  const float* b1 = (const float*)d_in[4];
  const float* W2 = (const float*)d_in[5];
  const float* b2 = (const float*)d_in[6];
  const float* W3 = (const float*)d_in[7];
  const float* b3 = (const float*)d_in[8];
  float* out = (float*)d_out;

  char* ws = (char*)d_ws;
  size_t o = 0;
  auto alloc = [&](size_t bytes) {
    char* p = ws + o;
    o += (bytes + 255) & ~(size_t)255;
    return p;
  };
  __half* xh   = (__half*)alloc((size_t)TK * DD * 2);
  __half* w1t  = (__half*)alloc((size_t)EE * DD * II * 2);
  __half* w2t  = (__half*)alloc((size_t)EE * II * HH * 2);
  __half* w3t  = (__half*)alloc((size_t)EE * HH * DD * 2);
  __half* h1   = (__half*)alloc((size_t)2 * TK * II * 2);
  __half* h2   = (__half*)alloc((size_t)2 * TK * HH * 2);
  __half* yc   = (__half*)alloc((size_t)2 * TK * DD * 2);
  int*   idxL  = (int*)alloc(2 * TK * 4);
  int*   sel   = (int*)alloc(2 * TK * 4);
  float* wTok  = (float*)alloc(2 * TK * 4);
  int*   posT  = (int*)alloc(2 * TK * 4);
  int*   counts  = (int*)alloc(256);
  int*   offsets = (int*)alloc(256);
  int*   cursors = (int*)alloc(256);
  if (o > ws_size) return;  // workspace too small -> loud absmax failure

  hipMemsetAsync(counts, 0, 256, stream);

  cvtT_kernel<<<dim3(II / 32, DD / 32, EE), dim3(32, 8), 0, stream>>>(W1, w1t, DD, II);
  cvtT_kernel<<<dim3(HH / 32, II / 32, EE), dim3(32, 8), 0, stream>>>(W2, w2t, II, HH);
  cvtT_kernel<<<dim3(DD / 32, HH / 32, EE), dim3(32, 8), 0, stream>>>(W3, w3t, HH, DD);
  router_kernel<<<TK / 4, 256, 0, stream>>>(x, Wr, br, counts, sel, wTok, xh);
  offsets_kernel<<<1, 64, 0, stream>>>(counts, offsets, cursors);
  scatter_kernel<<<TK / 256, 256, 0, stream>>>(sel, cursors, idxL, posT);

  ffn_gemm<DD, II, true,  true ><<<dim3(II / 128, 128, EE), 256, 0, stream>>>(
      xh, w1t, b1, h1, counts, offsets, idxL);
  ffn_gemm<II, HH, false, true ><<<dim3(HH / 128, 128, EE), 256, 0, stream>>>(
      h1, w2t, b2, h2, counts, offsets, idxL);
  ffn_gemm<HH, DD, false, false><<<dim3(DD / 128, 128, EE), 256, 0, stream>>>(
      h2, w3t, b3, yc, counts, offsets, idxL);

  combine_kernel<<<TK, 192, 0, stream>>>(yc, wTok, posT, out);
}

// Round 4
// 1650.352 us; speedup vs baseline: 1.1824x; 1.0223x over previous
//
#include <hip/hip_runtime.h>
#include <hip/hip_fp16.h>
#include <cstdint>
#include <cstddef>

// Problem constants (setup_inputs: B=8,S=2048,D=768,E=8,I=3072,H=1536,top_k=2)
#define TK 16384   // tokens
#define DD 768
#define EE 8
#define II 3072
#define HH 1536

typedef _Float16 half8 __attribute__((ext_vector_type(8)));
typedef float floatx4 __attribute__((ext_vector_type(4)));

typedef const __attribute__((address_space(1))) uint32_t* gptr_t;
typedef __attribute__((address_space(3))) uint32_t* lptr_t;

#define GLOAD_LDS16(gp, lp) __builtin_amdgcn_global_load_lds( \
    (gptr_t)(const void*)(gp), (lptr_t)(void*)(lp), 16, 0, 0)

// ------- fp32 [E][K][N] -> fp16 [E][N][K] transpose-convert -------
__global__ void cvtT_kernel(const float* __restrict__ in, __half* __restrict__ out,
                            int K, int N) {
  __shared__ float tile[32][33];
  int e = blockIdx.z;
  const float* inp = in + (size_t)e * K * N;
  __half* outp = out + (size_t)e * K * N;
  int n0 = blockIdx.x * 32, k0 = blockIdx.y * 32;
  int tx = threadIdx.x, ty = threadIdx.y;
#pragma unroll
  for (int i = 0; i < 4; ++i)
    tile[ty + i * 8][tx] = inp[(size_t)(k0 + ty + i * 8) * N + n0 + tx];
  __syncthreads();
#pragma unroll
  for (int i = 0; i < 4; ++i)
    outp[(size_t)(n0 + ty + i * 8) * K + k0 + tx] = __float2half(tile[tx][ty + i * 8]);
}

// ------- router: fp32 logits, top-2, softmax; also emits xh (fp16 copy of x) -------
__global__ __launch_bounds__(256)
void router_kernel(const float* __restrict__ x, const float* __restrict__ Wr,
                   const float* __restrict__ br, int* __restrict__ counts,
                   int* __restrict__ sel, float* __restrict__ wTok,
                   __half* __restrict__ xh) {
  __shared__ float wr_s[EE * DD];  // transposed [e][d], 24KB
  for (int i = threadIdx.x; i < EE * DD; i += 256) {
    int d = i >> 3, e = i & 7;
    wr_s[e * DD + d] = Wr[i];
  }
  __syncthreads();
  int wid = threadIdx.x >> 6, lane = threadIdx.x & 63;
  int t = blockIdx.x * 4 + wid;
  const float* xt = x + (size_t)t * DD;
  float acc[EE];
#pragma unroll
  for (int e = 0; e < EE; ++e) acc[e] = 0.f;
  for (int d = lane; d < DD; d += 64) {
    float xv = xt[d];
#pragma unroll
    for (int e = 0; e < EE; ++e) acc[e] += xv * wr_s[e * DD + d];
  }
#pragma unroll
  for (int off = 32; off > 0; off >>= 1)
#pragma unroll
    for (int e = 0; e < EE; ++e) acc[e] += __shfl_xor(acc[e], off);
  if (lane == 0) {
    float v[EE];
#pragma unroll
    for (int e = 0; e < EE; ++e) v[e] = acc[e] + br[e];
    int i0 = 0;
#pragma unroll
    for (int e = 1; e < EE; ++e) if (v[e] > v[i0]) i0 = e;
    int i1 = (i0 == 0) ? 1 : 0;
#pragma unroll
    for (int e = 0; e < EE; ++e) if (e != i0 && v[e] > v[i1] && e != i1) { if (v[e] > v[i1]) i1 = e; }
    float e1 = __expf(v[i1] - v[i0]);
    float s = 1.f / (1.f + e1);
    sel[2 * t] = i0; sel[2 * t + 1] = i1;
    wTok[2 * t] = s; wTok[2 * t + 1] = e1 * s;
    atomicAdd(&counts[i0], 1);
    atomicAdd(&counts[i1], 1);
  }
  // fused x -> fp16 conversion for this wave's token row (replaces cvt_kernel)
  const float4* xr = (const float4*)xt;
  uint2* xo = (uint2*)(xh + (size_t)t * DD);
#pragma unroll
  for (int j = 0; j < 3; ++j) {
    float4 v = xr[lane + j * 64];
    __half2 a = __floats2half2_rn(v.x, v.y);
    __half2 b = __floats2half2_rn(v.z, v.w);
    uint2 p;
    p.x = *(const unsigned int*)&a;
    p.y = *(const unsigned int*)&b;
    xo[lane + j * 64] = p;
  }
}

// ---------------- offsets (prefix over 8) ----------------
__global__ void offsets_kernel(const int* __restrict__ counts, int* __restrict__ offsets,
                               int* __restrict__ cursors) {
  if (threadIdx.x == 0) {
    int o = 0;
    for (int e = 0; e < EE; ++e) { offsets[e] = o; cursors[e] = o; o += counts[e]; }
  }
}

// ---------------- scatter token->slot ----------------
__global__ void scatter_kernel(const int* __restrict__ sel, int* __restrict__ cursors,
                               int* __restrict__ idxList, int* __restrict__ posTok) {
  int t = blockIdx.x * 256 + threadIdx.x;
  if (t < TK) {
#pragma unroll
    for (int k = 0; k < 2; ++k) {
      int e = sel[2 * t + k];
      int p = atomicAdd(&cursors[e], 1);
      idxList[p] = t;
      posTok[2 * t + k] = p;
    }
  }
}

// ---------------- FFN GEMM: C[cnt,N] = A[cnt,K] @ Wt[e] (+bias, gelu) ----------------
// 128x128 tile, BK=64, 4 waves (2x2), 16x16x32 f16 MFMA, XOR-swizzled LDS.
// T3+T4: LDS double buffer with COUNTED vmcnt across raw s_barrier:
//   stage(t+1 -> NXT); s_waitcnt vmcnt(8)   <- only tile t's 8 loads retired;
//                                              the 8 just-issued stay in flight
//   s_barrier; ds_read+MFMA on CUR (compiler lgkm waits); s_barrier
// RAW on CUR: every wave passed its own vmcnt(8) before the leading barrier.
// WAR on NXT-being-staged: trailing barrier of previous tile ordered all reads
// of that buffer before this tile's stage issue.
template<int KD, int ND, bool GATHER, bool GELU>
__global__ __launch_bounds__(256, 2)
void ffn_gemm(const __half* __restrict__ A, const __half* __restrict__ Wt,
              const float* __restrict__ Bias, __half* __restrict__ Out,
              const int* __restrict__ counts, const int* __restrict__ offsets,
              const int* __restrict__ idxList) {
  constexpr int NT = KD / 64;                 // 12 / 48 / 24 — all even
  const int e = blockIdx.z;
  const int cnt = counts[e];
  const int m0 = blockIdx.y * 128;
  if (cnt == 0 || m0 >= cnt) return;
  const int off = offsets[e];
  const int n0 = blockIdx.x * 128;
  const __half* We = Wt + (size_t)e * KD * ND;
  const float* be = Bias + (size_t)e * ND;

  __shared__ __align__(16) __half As[2][128 * 64];
  __shared__ __align__(16) __half Bs[2][128 * 64];

  const int tid = threadIdx.x;

  // staging source addresses: slot s = i*256+tid; row = s/8, scol = s%8
  // global col pre-swizzled: (scol ^ (row&7))*8  (matches swizzled read below)
  const __half* abase[4];
  const __half* bbase[4];
#pragma unroll
  for (int i = 0; i < 4; ++i) {
    int s = i * 256 + tid;
    int row = s >> 3;
    int sc = s & 7;
    int r = m0 + row; if (r > cnt - 1) r = cnt - 1;  // clamp tail (writes guarded)
    size_t arow = GATHER ? (size_t)idxList[off + r] : (size_t)(off + r);
    abase[i] = A + arow * KD + ((sc ^ (row & 7)) << 3);
    bbase[i] = We + (size_t)(n0 + row) * KD + ((sc ^ (row & 7)) << 3);
  }

  floatx4 acc[4][4];
#pragma unroll
  for (int mi = 0; mi < 4; ++mi)
#pragma unroll
    for (int ni = 0; ni < 4; ++ni) acc[mi][ni] = (floatx4){0.f, 0.f, 0.f, 0.f};

  const int lane = tid & 63;
  const int wv = tid >> 6;
  const int wr = wv >> 1, wc = wv & 1;
  const int lrow = lane & 15, lg = lane >> 4;

  int aoff[4][2], boff[4][2];
#pragma unroll
  for (int mi = 0; mi < 4; ++mi) {
    int row = wr * 64 + mi * 16 + lrow;
#pragma unroll
    for (int kk = 0; kk < 2; ++kk) {
      int slot = kk * 4 + lg;
      aoff[mi][kk] = row * 64 + ((slot ^ (row & 7)) << 3);
    }
  }
#pragma unroll
  for (int ni = 0; ni < 4; ++ni) {
    int row = wc * 64 + ni * 16 + lrow;
#pragma unroll
    for (int kk = 0; kk < 2; ++kk) {
      int slot = kk * 4 + lg;
      boff[ni][kk] = row * 64 + ((slot ^ (row & 7)) << 3);
    }
  }

  // ---- prologue: stage tile 0 into buf 0 (no drain — loop's vmcnt covers it) ----
#pragma unroll
  for (int i = 0; i < 4; ++i) GLOAD_LDS16(abase[i], &As[0][i * 2048 + tid * 8]);
#pragma unroll
  for (int i = 0; i < 4; ++i) GLOAD_LDS16(bbase[i], &Bs[0][i * 2048 + tid * 8]);

#define TILE(CUR, NXT, TT)                                                    \
  {                                                                           \
    if ((TT) + 1 < NT) {                                                      \
      _Pragma("unroll") for (int i = 0; i < 4; ++i)                           \
        GLOAD_LDS16(abase[i] + ((TT) + 1) * 64, &As[NXT][i * 2048 + tid * 8]);\
      _Pragma("unroll") for (int i = 0; i < 4; ++i)                           \
        GLOAD_LDS16(bbase[i] + ((TT) + 1) * 64, &Bs[NXT][i * 2048 + tid * 8]);\
      asm volatile("s_waitcnt vmcnt(8)" ::: "memory");                        \
    } else {                                                                  \
      asm volatile("s_waitcnt vmcnt(0)" ::: "memory");                        \
    }                                                                         \
    __builtin_amdgcn_s_barrier();                                             \
    __builtin_amdgcn_sched_barrier(0);                                        \
    _Pragma("unroll") for (int kk = 0; kk < 2; ++kk) {                        \
      half8 af[4], bf[4];                                                     \
      _Pragma("unroll") for (int mi = 0; mi < 4; ++mi)                        \
        af[mi] = *(const half8*)&As[CUR][aoff[mi][kk]];                       \
      _Pragma("unroll") for (int ni = 0; ni < 4; ++ni)                        \
        bf[ni] = *(const half8*)&Bs[CUR][boff[ni][kk]];                       \
      _Pragma("unroll") for (int mi = 0; mi < 4; ++mi)                        \
        _Pragma("unroll") for (int ni = 0; ni < 4; ++ni)                      \
          acc[mi][ni] = __builtin_amdgcn_mfma_f32_16x16x32_f16(               \
              af[mi], bf[ni], acc[mi][ni], 0, 0, 0);                          \
    }                                                                         \
    __builtin_amdgcn_sched_barrier(0);                                        \
    __builtin_amdgcn_s_barrier();                                             \
  }

  for (int t = 0; t < NT; t += 2) {
    TILE(0, 1, t)
    TILE(1, 0, t + 1)
  }
#undef TILE

  // epilogue: C row = (lane>>4)*4 + j, col = lane&15 per 16x16 fragment
#pragma unroll
  for (int ni = 0; ni < 4; ++ni) {
    int col = n0 + wc * 64 + ni * 16 + lrow;
    float bv = be[col];
#pragma unroll
    for (int mi = 0; mi < 4; ++mi) {
      int rbase = m0 + wr * 64 + mi * 16 + lg * 4;
#pragma unroll
      for (int j = 0; j < 4; ++j) {
        int r = rbase + j;
        if (r < cnt) {
          float v = acc[mi][ni][j] + bv;
          if (GELU) v = 0.5f * v * (1.f + erff(v * 0.70710678118654752f));
          Out[(size_t)(off + r) * ND + col] = __float2half(v);
        }
      }
    }
  }
}

// ---------------- combine: out[t] = w0*yc[p0] + w1*yc[p1] ----------------
__global__ void combine_kernel(const __half* __restrict__ yc, const float* __restrict__ wTok,
                               const int* __restrict__ posTok, float* __restrict__ out) {
  int t = blockIdx.x;
  int d = threadIdx.x * 4;
  if (d >= DD) return;
  float w0 = wTok[2 * t], w1 = wTok[2 * t + 1];
  const __half2* a = (const __half2*)(yc + (size_t)posTok[2 * t] * DD + d);
  const __half2* b = (const __half2*)(yc + (size_t)posTok[2 * t + 1] * DD + d);
  float2 a0 = __half22float2(a[0]), a1 = __half22float2(a[1]);
  float2 b0 = __half22float2(b[0]), b1 = __half22float2(b[1]);
  float4 r;
  r.x = w0 * a0.x + w1 * b0.x;
  r.y = w0 * a0.y + w1 * b0.y;
  r.z = w0 * a1.x + w1 * b1.x;
  r.w = w0 * a1.y + w1 * b1.y;
  *(float4*)(out + (size_t)t * DD + d) = r;
}

extern "C" void kernel_launch(void* const* d_in, const int* in_sizes, int n_in,
                              void* d_out, int out_size, void* d_ws, size_t ws_size,
                              hipStream_t stream) {
  const float* x  = (const float*)d_in[0];
  const float* Wr = (const float*)d_in[1];
  const float* br = (const float*)d_in[2];
  const float* W1 = (const float*)d_in[3];
  const float* b1 = (const float*)d_in[4];
  const float* W2 = (const float*)d_in[5];
  const float* b2 = (const float*)d_in[6];
  const float* W3 = (const float*)d_in[7];
  const float* b3 = (const float*)d_in[8];
  float* out = (float*)d_out;

  char* ws = (char*)d_ws;
  size_t o = 0;
  auto alloc = [&](size_t bytes) {
    char* p = ws + o;
    o += (bytes + 255) & ~(size_t)255;
    return p;
  };
  __half* xh   = (__half*)alloc((size_t)TK * DD * 2);
  __half* w1t  = (__half*)alloc((size_t)EE * DD * II * 2);
  __half* w2t  = (__half*)alloc((size_t)EE * II * HH * 2);
  __half* w3t  = (__half*)alloc((size_t)EE * HH * DD * 2);
  __half* h1   = (__half*)alloc((size_t)2 * TK * II * 2);
  __half* h2   = (__half*)alloc((size_t)2 * TK * HH * 2);
  __half* yc   = (__half*)alloc((size_t)2 * TK * DD * 2);
  int*   idxL  = (int*)alloc(2 * TK * 4);
  int*   sel   = (int*)alloc(2 * TK * 4);
  float* wTok  = (float*)alloc(2 * TK * 4);
  int*   posT  = (int*)alloc(2 * TK * 4);
  int*   counts  = (int*)alloc(256);
  int*   offsets = (int*)alloc(256);
  int*   cursors = (int*)alloc(256);
  if (o > ws_size) return;  // workspace too small -> loud absmax failure

  hipMemsetAsync(counts, 0, 256, stream);

  cvtT_kernel<<<dim3(II / 32, DD / 32, EE), dim3(32, 8), 0, stream>>>(W1, w1t, DD, II);
  cvtT_kernel<<<dim3(HH / 32, II / 32, EE), dim3(32, 8), 0, stream>>>(W2, w2t, II, HH);
  cvtT_kernel<<<dim3(DD / 32, HH / 32, EE), dim3(32, 8), 0, stream>>>(W3, w3t, HH, DD);
  router_kernel<<<TK / 4, 256, 0, stream>>>(x, Wr, br, counts, sel, wTok, xh);
  offsets_kernel<<<1, 64, 0, stream>>>(counts, offsets, cursors);
  scatter_kernel<<<TK / 256, 256, 0, stream>>>(sel, cursors, idxL, posT);

  ffn_gemm<DD, II, true,  true ><<<dim3(II / 128, 128, EE), 256, 0, stream>>>(
      xh, w1t, b1, h1, counts, offsets, idxL);
  ffn_gemm<II, HH, false, true ><<<dim3(HH / 128, 128, EE), 256, 0, stream>>>(
      h1, w2t, b2, h2, counts, offsets, idxL);
  ffn_gemm<HH, DD, false, false><<<dim3(DD / 128, 128, EE), 256, 0, stream>>>(
      h2, w3t, b3, yc, counts, offsets, idxL);

  combine_kernel<<<TK, 192, 0, stream>>>(yc, wTok, posT, out);
}

// Round 5
// 1593.834 us; speedup vs baseline: 1.2243x; 1.0355x over previous
//
#include <hip/hip_runtime.h>
#include <hip/hip_fp16.h>
#include <cstdint>
#include <cstddef>

// Problem constants (setup_inputs: B=8,S=2048,D=768,E=8,I=3072,H=1536,top_k=2)
#define TK 16384   // tokens
#define DD 768
#define EE 8
#define II 3072
#define HH 1536

typedef _Float16 half8 __attribute__((ext_vector_type(8)));
typedef float floatx4 __attribute__((ext_vector_type(4)));

typedef const __attribute__((address_space(1))) uint32_t* gptr_t;
typedef __attribute__((address_space(3))) uint32_t* lptr_t;

#define GLOAD_LDS16(gp, lp) __builtin_amdgcn_global_load_lds( \
    (gptr_t)(const void*)(gp), (lptr_t)(void*)(lp), 16, 0, 0)

// Bijective XCD chunk swizzle: all gridDim.x N-tiles of one (e,m) land on one
// XCD contiguously (A-panel L2 reuse). Bijective because gridDim.z==8 makes
// total % (8*G) == 0 with G = gridDim.x.  [T1/m204]
__device__ inline void xcd_swizzle(int& e, int& m, int& n) {
  int gx = gridDim.x, gy = gridDim.y;
  int f = (blockIdx.z * gy + blockIdx.y) * gx + blockIdx.x;
  int xcd = f & 7, idx = f >> 3;
  int chunk = idx / gx, pos = idx - chunk * gx;
  int logical = chunk * (8 * gx) + xcd * gx + pos;
  int mn = gy * gx;
  e = logical / mn;
  int rem = logical - e * mn;
  m = rem / gx;
  n = rem - m * gx;
}

// ------- fp32 [E][K][N] -> fp16 [E][N][K] transpose-convert -------
__global__ void cvtT_kernel(const float* __restrict__ in, __half* __restrict__ out,
                            int K, int N) {
  __shared__ float tile[32][33];
  int e = blockIdx.z;
  const float* inp = in + (size_t)e * K * N;
  __half* outp = out + (size_t)e * K * N;
  int n0 = blockIdx.x * 32, k0 = blockIdx.y * 32;
  int tx = threadIdx.x, ty = threadIdx.y;
#pragma unroll
  for (int i = 0; i < 4; ++i)
    tile[ty + i * 8][tx] = inp[(size_t)(k0 + ty + i * 8) * N + n0 + tx];
  __syncthreads();
#pragma unroll
  for (int i = 0; i < 4; ++i)
    outp[(size_t)(n0 + ty + i * 8) * K + k0 + tx] = __float2half(tile[tx][ty + i * 8]);
}

// ------- router: fp32 logits, top-2, softmax; also emits xh (fp16 copy of x) -------
__global__ __launch_bounds__(256)
void router_kernel(const float* __restrict__ x, const float* __restrict__ Wr,
                   const float* __restrict__ br, int* __restrict__ counts,
                   int* __restrict__ sel, float* __restrict__ wTok,
                   __half* __restrict__ xh) {
  __shared__ float wr_s[EE * DD];  // transposed [e][d], 24KB
  for (int i = threadIdx.x; i < EE * DD; i += 256) {
    int d = i >> 3, e = i & 7;
    wr_s[e * DD + d] = Wr[i];
  }
  __syncthreads();
  int wid = threadIdx.x >> 6, lane = threadIdx.x & 63;
  int t = blockIdx.x * 4 + wid;
  const float* xt = x + (size_t)t * DD;
  float acc[EE];
#pragma unroll
  for (int e = 0; e < EE; ++e) acc[e] = 0.f;
  for (int d = lane; d < DD; d += 64) {
    float xv = xt[d];
#pragma unroll
    for (int e = 0; e < EE; ++e) acc[e] += xv * wr_s[e * DD + d];
  }
#pragma unroll
  for (int off = 32; off > 0; off >>= 1)
#pragma unroll
    for (int e = 0; e < EE; ++e) acc[e] += __shfl_xor(acc[e], off);
  if (lane == 0) {
    float v[EE];
#pragma unroll
    for (int e = 0; e < EE; ++e) v[e] = acc[e] + br[e];
    int i0 = 0;
#pragma unroll
    for (int e = 1; e < EE; ++e) if (v[e] > v[i0]) i0 = e;
    int i1 = (i0 == 0) ? 1 : 0;
#pragma unroll
    for (int e = 0; e < EE; ++e) if (e != i0 && v[e] > v[i1] && e != i1) { if (v[e] > v[i1]) i1 = e; }
    float e1 = __expf(v[i1] - v[i0]);
    float s = 1.f / (1.f + e1);
    sel[2 * t] = i0; sel[2 * t + 1] = i1;
    wTok[2 * t] = s; wTok[2 * t + 1] = e1 * s;
    atomicAdd(&counts[i0], 1);
    atomicAdd(&counts[i1], 1);
  }
  // fused x -> fp16 conversion for this wave's token row (replaces cvt_kernel)
  const float4* xr = (const float4*)xt;
  uint2* xo = (uint2*)(xh + (size_t)t * DD);
#pragma unroll
  for (int j = 0; j < 3; ++j) {
    float4 v = xr[lane + j * 64];
    __half2 a = __floats2half2_rn(v.x, v.y);
    __half2 b = __floats2half2_rn(v.z, v.w);
    uint2 p;
    p.x = *(const unsigned int*)&a;
    p.y = *(const unsigned int*)&b;
    xo[lane + j * 64] = p;
  }
}

// ---------------- offsets (prefix over 8) ----------------
__global__ void offsets_kernel(const int* __restrict__ counts, int* __restrict__ offsets,
                               int* __restrict__ cursors) {
  if (threadIdx.x == 0) {
    int o = 0;
    for (int e = 0; e < EE; ++e) { offsets[e] = o; cursors[e] = o; o += counts[e]; }
  }
}

// ---------------- scatter token->slot ----------------
__global__ void scatter_kernel(const int* __restrict__ sel, int* __restrict__ cursors,
                               int* __restrict__ idxList, int* __restrict__ posTok) {
  int t = blockIdx.x * 256 + threadIdx.x;
  if (t < TK) {
#pragma unroll
    for (int k = 0; k < 2; ++k) {
      int e = sel[2 * t + k];
      int p = atomicAdd(&cursors[e], 1);
      idxList[p] = t;
      posTok[2 * t + k] = p;
    }
  }
}

// ---------------- FFN GEMM (2-phase 128x128, stages 1 & 3) ----------------
// T3+T4: dbuf + counted vmcnt across raw s_barrier (see R4 notes).
template<int KD, int ND, bool GATHER, bool GELU>
__global__ __launch_bounds__(256, 2)
void ffn_gemm(const __half* __restrict__ A, const __half* __restrict__ Wt,
              const float* __restrict__ Bias, __half* __restrict__ Out,
              const int* __restrict__ counts, const int* __restrict__ offsets,
              const int* __restrict__ idxList) {
  constexpr int NT = KD / 64;
  int e, mblk, nblk;
  xcd_swizzle(e, mblk, nblk);
  const int cnt = counts[e];
  const int m0 = mblk * 128;
  if (cnt == 0 || m0 >= cnt) return;
  const int off = offsets[e];
  const int n0 = nblk * 128;
  const __half* We = Wt + (size_t)e * KD * ND;
  const float* be = Bias + (size_t)e * ND;

  __shared__ __align__(16) __half As[2][128 * 64];
  __shared__ __align__(16) __half Bs[2][128 * 64];

  const int tid = threadIdx.x;

  const __half* abase[4];
  const __half* bbase[4];
#pragma unroll
  for (int i = 0; i < 4; ++i) {
    int s = i * 256 + tid;
    int row = s >> 3;
    int sc = s & 7;
    int r = m0 + row; if (r > cnt - 1) r = cnt - 1;  // clamp tail (writes guarded)
    size_t arow = GATHER ? (size_t)idxList[off + r] : (size_t)(off + r);
    abase[i] = A + arow * KD + ((sc ^ (row & 7)) << 3);
    bbase[i] = We + (size_t)(n0 + row) * KD + ((sc ^ (row & 7)) << 3);
  }

  floatx4 acc[4][4];
#pragma unroll
  for (int mi = 0; mi < 4; ++mi)
#pragma unroll
    for (int ni = 0; ni < 4; ++ni) acc[mi][ni] = (floatx4){0.f, 0.f, 0.f, 0.f};

  const int lane = tid & 63;
  const int wv = tid >> 6;
  const int wr = wv >> 1, wc = wv & 1;
  const int lrow = lane & 15, lg = lane >> 4;

  int aoff[4][2], boff[4][2];
#pragma unroll
  for (int mi = 0; mi < 4; ++mi) {
    int row = wr * 64 + mi * 16 + lrow;
#pragma unroll
    for (int kk = 0; kk < 2; ++kk) {
      int slot = kk * 4 + lg;
      aoff[mi][kk] = row * 64 + ((slot ^ (row & 7)) << 3);
    }
  }
#pragma unroll
  for (int ni = 0; ni < 4; ++ni) {
    int row = wc * 64 + ni * 16 + lrow;
#pragma unroll
    for (int kk = 0; kk < 2; ++kk) {
      int slot = kk * 4 + lg;
      boff[ni][kk] = row * 64 + ((slot ^ (row & 7)) << 3);
    }
  }

#pragma unroll
  for (int i = 0; i < 4; ++i) GLOAD_LDS16(abase[i], &As[0][i * 2048 + tid * 8]);
#pragma unroll
  for (int i = 0; i < 4; ++i) GLOAD_LDS16(bbase[i], &Bs[0][i * 2048 + tid * 8]);

#define TILE(CUR, NXT, TT)                                                    \
  {                                                                           \
    if ((TT) + 1 < NT) {                                                      \
      _Pragma("unroll") for (int i = 0; i < 4; ++i)                           \
        GLOAD_LDS16(abase[i] + ((TT) + 1) * 64, &As[NXT][i * 2048 + tid * 8]);\
      _Pragma("unroll") for (int i = 0; i < 4; ++i)                           \
        GLOAD_LDS16(bbase[i] + ((TT) + 1) * 64, &Bs[NXT][i * 2048 + tid * 8]);\
      asm volatile("s_waitcnt vmcnt(8)" ::: "memory");                        \
    } else {                                                                  \
      asm volatile("s_waitcnt vmcnt(0)" ::: "memory");                        \
    }                                                                         \
    __builtin_amdgcn_s_barrier();                                             \
    __builtin_amdgcn_sched_barrier(0);                                        \
    _Pragma("unroll") for (int kk = 0; kk < 2; ++kk) {                        \
      half8 af[4], bf[4];                                                     \
      _Pragma("unroll") for (int mi = 0; mi < 4; ++mi)                        \
        af[mi] = *(const half8*)&As[CUR][aoff[mi][kk]];                       \
      _Pragma("unroll") for (int ni = 0; ni < 4; ++ni)                        \
        bf[ni] = *(const half8*)&Bs[CUR][boff[ni][kk]];                       \
      _Pragma("unroll") for (int mi = 0; mi < 4; ++mi)                        \
        _Pragma("unroll") for (int ni = 0; ni < 4; ++ni)                      \
          acc[mi][ni] = __builtin_amdgcn_mfma_f32_16x16x32_f16(               \
              af[mi], bf[ni], acc[mi][ni], 0, 0, 0);                          \
    }                                                                         \
    __builtin_amdgcn_sched_barrier(0);                                        \
    __builtin_amdgcn_s_barrier();                                             \
  }

  for (int t = 0; t < NT; t += 2) {
    TILE(0, 1, t)
    TILE(1, 0, t + 1)
  }
#undef TILE

#pragma unroll
  for (int ni = 0; ni < 4; ++ni) {
    int col = n0 + wc * 64 + ni * 16 + lrow;
    float bv = be[col];
#pragma unroll
    for (int mi = 0; mi < 4; ++mi) {
      int rbase = m0 + wr * 64 + mi * 16 + lg * 4;
#pragma unroll
      for (int j = 0; j < 4; ++j) {
        int r = rbase + j;
        if (r < cnt) {
          float v = acc[mi][ni][j] + bv;
          if (GELU) v = 0.5f * v * (1.f + erff(v * 0.70710678118654752f));
          Out[(size_t)(off + r) * ND + col] = __float2half(v);
        }
      }
    }
  }
}

// ---------------- FFN GEMM (8-phase 256x256, stage 2) ----------------
// R2 schedule (passed correctness), fixed: launch_bounds(512,1) -> VGPR<=256
// (R2's (512,2) clamped VGPR to 128 and starved the 128-VGPR accumulator).
template<int KD, int ND, bool GELU>
__global__ __launch_bounds__(512, 1)
void ffn_gemm8(const __half* __restrict__ A, const __half* __restrict__ Wt,
               const float* __restrict__ Bias, __half* __restrict__ Out,
               const int* __restrict__ counts, const int* __restrict__ offsets) {
  constexpr int NT = KD / 64;
  int e, mblk, nblk;
  xcd_swizzle(e, mblk, nblk);
  const int cnt = counts[e];
  const int m0 = mblk * 256;
  if (cnt == 0 || m0 >= cnt) return;
  const int off = offsets[e];
  const int n0 = nblk * 256;
  const __half* We = Wt + (size_t)e * KD * ND;
  const float* be = Bias + (size_t)e * ND;

  __shared__ __align__(16) __half As[2][256 * 64];
  __shared__ __align__(16) __half Bs[2][256 * 64];

  const int tid = threadIdx.x;
  const int srow = tid >> 3;                 // 0..63 row within quarter
  const int swz = ((tid & 7) ^ (srow & 7)) << 3;

  const __half* aptr[4];
  const __half* bptr[4];
#pragma unroll
  for (int q = 0; q < 4; ++q) {
    int gr = m0 + q * 64 + srow;
    if (gr > cnt - 1) gr = cnt - 1;          // clamp tail (writes guarded)
    aptr[q] = A + (size_t)(off + gr) * KD + swz;
    bptr[q] = We + (size_t)(n0 + q * 64 + srow) * KD + swz;
  }

#define STAGE_A(BUF, Q, TS) GLOAD_LDS16(aptr[Q] + (TS) * 64, &As[BUF][(Q) * 4096 + tid * 8])
#define STAGE_B(BUF, Q, TS) GLOAD_LDS16(bptr[Q] + (TS) * 64, &Bs[BUF][(Q) * 4096 + tid * 8])

  const int lane = tid & 63, wv = tid >> 6;
  const int wr = wv >> 2, wc = wv & 3;       // 2 x 4 wave grid
  const int lrow = lane & 15, lg = lane >> 4;
  const int rowa = wr * 128 + lrow;
  const int rowb = wc * 64 + lrow;
  int aoff[2], boff[2];
#pragma unroll
  for (int kk = 0; kk < 2; ++kk) {
    aoff[kk] = rowa * 64 + (((kk * 4 + lg) ^ (rowa & 7)) << 3);
    boff[kk] = rowb * 64 + (((kk * 4 + lg) ^ (rowb & 7)) << 3);
  }

  floatx4 acc[8][4];
#pragma unroll
  for (int mi = 0; mi < 8; ++mi)
#pragma unroll
    for (int ni = 0; ni < 4; ++ni) acc[mi][ni] = (floatx4){0.f, 0.f, 0.f, 0.f};

  // ---- prologue: tile0 fully, tile1 minus B-q2,q3 (staged at t0.a) ----
#pragma unroll
  for (int q = 0; q < 4; ++q) STAGE_A(0, q, 0);
#pragma unroll
  for (int q = 0; q < 4; ++q) STAGE_B(0, q, 0);
#pragma unroll
  for (int q = 0; q < 4; ++q) STAGE_A(1, q, 1);
  STAGE_B(1, 0, 1);
  STAGE_B(1, 1, 1);
  asm volatile("s_waitcnt vmcnt(6)" ::: "memory");   // tile0's 8 quarters landed
  __builtin_amdgcn_s_barrier();

#define BAR() __builtin_amdgcn_s_barrier()
#define WLG() do { asm volatile("s_waitcnt lgkmcnt(0)" ::: "memory"); \
                   __builtin_amdgcn_sched_barrier(0); } while (0)
#define P1() __builtin_amdgcn_s_setprio(1)
#define P0() __builtin_amdgcn_s_setprio(0)
#define MMQ(AF, BF, MB, NB) \
  _Pragma("unroll") for (int kk = 0; kk < 2; ++kk) \
  _Pragma("unroll") for (int mi = 0; mi < 4; ++mi) \
  _Pragma("unroll") for (int ni = 0; ni < 2; ++ni) \
    acc[(MB) + mi][(NB) + ni] = __builtin_amdgcn_mfma_f32_16x16x32_f16( \
        AF[mi][kk], BF[ni][kk], acc[(MB) + mi][(NB) + ni], 0, 0, 0);

#define PHASES(CUR, NXT, TT) { \
  const __half* Ac = &As[CUR][0]; \
  const __half* Bc = &Bs[CUR][0]; \
  half8 af[4][2], bf0[2][2], bf1[2][2]; \
  _Pragma("unroll") for (int mi = 0; mi < 4; ++mi) \
  _Pragma("unroll") for (int kk = 0; kk < 2; ++kk) \
    af[mi][kk] = *(const half8*)&Ac[aoff[kk] + mi * 1024]; \
  _Pragma("unroll") for (int ni = 0; ni < 2; ++ni) \
  _Pragma("unroll") for (int kk = 0; kk < 2; ++kk) \
    bf0[ni][kk] = *(const half8*)&Bc[boff[kk] + ni * 1024]; \
  if ((TT) + 1 < NT) { STAGE_B(NXT, 2, (TT) + 1); STAGE_B(NXT, 3, (TT) + 1); } \
  BAR(); WLG(); P1(); MMQ(af, bf0, 0, 0); P0(); BAR(); \
  _Pragma("unroll") for (int ni = 0; ni < 2; ++ni) \
  _Pragma("unroll") for (int kk = 0; kk < 2; ++kk) \
    bf1[ni][kk] = *(const half8*)&Bc[boff[kk] + (ni + 2) * 1024]; \
  if ((TT) + 2 < NT) { STAGE_A(CUR, 0, (TT) + 2); STAGE_A(CUR, 2, (TT) + 2); } \
  BAR(); WLG(); P1(); MMQ(af, bf1, 0, 2); P0(); BAR(); \
  _Pragma("unroll") for (int mi = 0; mi < 4; ++mi) \
  _Pragma("unroll") for (int kk = 0; kk < 2; ++kk) \
    af[mi][kk] = *(const half8*)&Ac[aoff[kk] + (mi + 4) * 1024]; \
  if ((TT) + 2 < NT) { STAGE_B(CUR, 0, (TT) + 2); STAGE_B(CUR, 1, (TT) + 2); } \
  BAR(); WLG(); P1(); MMQ(af, bf0, 4, 0); P0(); BAR(); \
  if ((TT) + 2 < NT) { STAGE_A(CUR, 1, (TT) + 2); STAGE_A(CUR, 3, (TT) + 2); } \
  BAR(); P1(); MMQ(af, bf1, 4, 2); P0(); \
  if ((TT) + 2 < NT) { asm volatile("s_waitcnt vmcnt(6)" ::: "memory"); } \
  else              { asm volatile("s_waitcnt vmcnt(0)" ::: "memory"); } \
  BAR(); }

  for (int t = 0; t < NT; t += 2) {
    PHASES(0, 1, t)
    PHASES(1, 0, t + 1)
  }

  // ---- epilogue: bias + optional erf-GELU, guarded rows ----
  const int crow = m0 + wr * 128 + lg * 4;
  const int ccol = n0 + wc * 64 + lrow;
  float bv[4];
#pragma unroll
  for (int ni = 0; ni < 4; ++ni) bv[ni] = be[ccol + ni * 16];
#pragma unroll
  for (int mi = 0; mi < 8; ++mi) {
#pragma unroll
    for (int j = 0; j < 4; ++j) {
      int r = crow + mi * 16 + j;
      if (r < cnt) {
#pragma unroll
        for (int ni = 0; ni < 4; ++ni) {
          float v = acc[mi][ni][j] + bv[ni];
          if (GELU) v = 0.5f * v * (1.f + erff(v * 0.70710678118654752f));
          Out[(size_t)(off + r) * ND + ccol + ni * 16] = __float2half(v);
        }
      }
    }
  }
#undef STAGE_A
#undef STAGE_B
#undef BAR
#undef WLG
#undef P1
#undef P0
#undef MMQ
#undef PHASES
}

// ---------------- combine: out[t] = w0*yc[p0] + w1*yc[p1] ----------------
__global__ void combine_kernel(const __half* __restrict__ yc, const float* __restrict__ wTok,
                               const int* __restrict__ posTok, float* __restrict__ out) {
  int t = blockIdx.x;
  int d = threadIdx.x * 4;
  if (d >= DD) return;
  float w0 = wTok[2 * t], w1 = wTok[2 * t + 1];
  const __half2* a = (const __half2*)(yc + (size_t)posTok[2 * t] * DD + d);
  const __half2* b = (const __half2*)(yc + (size_t)posTok[2 * t + 1] * DD + d);
  float2 a0 = __half22float2(a[0]), a1 = __half22float2(a[1]);
  float2 b0 = __half22float2(b[0]), b1 = __half22float2(b[1]);
  float4 r;
  r.x = w0 * a0.x + w1 * b0.x;
  r.y = w0 * a0.y + w1 * b0.y;
  r.z = w0 * a1.x + w1 * b1.x;
  r.w = w0 * a1.y + w1 * b1.y;
  *(float4*)(out + (size_t)t * DD + d) = r;
}

extern "C" void kernel_launch(void* const* d_in, const int* in_sizes, int n_in,
                              void* d_out, int out_size, void* d_ws, size_t ws_size,
                              hipStream_t stream) {
  const float* x  = (const float*)d_in[0];
  const float* Wr = (const float*)d_in[1];
  const float* br = (const float*)d_in[2];
  const float* W1 = (const float*)d_in[3];
  const float* b1 = (const float*)d_in[4];
  const float* W2 = (const float*)d_in[5];
  const float* b2 = (const float*)d_in[6];
  const float* W3 = (const float*)d_in[7];
  const float* b3 = (const float*)d_in[8];
  float* out = (float*)d_out;

  char* ws = (char*)d_ws;
  size_t o = 0;
  auto alloc = [&](size_t bytes) {
    char* p = ws + o;
    o += (bytes + 255) & ~(size_t)255;
    return p;
  };
  __half* xh   = (__half*)alloc((size_t)TK * DD * 2);
  __half* w1t  = (__half*)alloc((size_t)EE * DD * II * 2);
  __half* w2t  = (__half*)alloc((size_t)EE * II * HH * 2);
  __half* w3t  = (__half*)alloc((size_t)EE * HH * DD * 2);
  __half* h1   = (__half*)alloc((size_t)2 * TK * II * 2);
  __half* h2   = (__half*)alloc((size_t)2 * TK * HH * 2);
  __half* yc   = (__half*)alloc((size_t)2 * TK * DD * 2);
  int*   idxL  = (int*)alloc(2 * TK * 4);
  int*   sel   = (int*)alloc(2 * TK * 4);
  float* wTok  = (float*)alloc(2 * TK * 4);
  int*   posT  = (int*)alloc(2 * TK * 4);
  int*   counts  = (int*)alloc(256);
  int*   offsets = (int*)alloc(256);
  int*   cursors = (int*)alloc(256);
  if (o > ws_size) return;  // workspace too small -> loud absmax failure

  hipMemsetAsync(counts, 0, 256, stream);

  cvtT_kernel<<<dim3(II / 32, DD / 32, EE), dim3(32, 8), 0, stream>>>(W1, w1t, DD, II);
  cvtT_kernel<<<dim3(HH / 32, II / 32, EE), dim3(32, 8), 0, stream>>>(W2, w2t, II, HH);
  cvtT_kernel<<<dim3(DD / 32, HH / 32, EE), dim3(32, 8), 0, stream>>>(W3, w3t, HH, DD);
  router_kernel<<<TK / 4, 256, 0, stream>>>(x, Wr, br, counts, sel, wTok, xh);
  offsets_kernel<<<1, 64, 0, stream>>>(counts, offsets, cursors);
  scatter_kernel<<<TK / 256, 256, 0, stream>>>(sel, cursors, idxL, posT);

  ffn_gemm<DD, II, true,  true ><<<dim3(II / 128, 128, EE), 256, 0, stream>>>(
      xh, w1t, b1, h1, counts, offsets, idxL);
  ffn_gemm8<II, HH, true ><<<dim3(HH / 256, 64, EE), 512, 0, stream>>>(
      h1, w2t, b2, h2, counts, offsets);
  ffn_gemm<HH, DD, false, false><<<dim3(DD / 128, 128, EE), 256, 0, stream>>>(
      h2, w3t, b3, yc, counts, offsets, idxL);

  combine_kernel<<<TK, 192, 0, stream>>>(yc, wTok, posT, out);
}

// Round 6
// 1505.223 us; speedup vs baseline: 1.2964x; 1.0589x over previous
//
#include <hip/hip_runtime.h>
#include <hip/hip_fp16.h>
#include <cstdint>
#include <cstddef>

// Problem constants (setup_inputs: B=8,S=2048,D=768,E=8,I=3072,H=1536,top_k=2)
#define TK 16384   // tokens
#define DD 768
#define EE 8
#define II 3072
#define HH 1536

typedef _Float16 half8 __attribute__((ext_vector_type(8)));
typedef float floatx4 __attribute__((ext_vector_type(4)));

typedef const __attribute__((address_space(1))) uint32_t* gptr_t;
typedef __attribute__((address_space(3))) uint32_t* lptr_t;

#define GLOAD_LDS16(gp, lp) __builtin_amdgcn_global_load_lds( \
    (gptr_t)(const void*)(gp), (lptr_t)(void*)(lp), 16, 0, 0)

// Bijective XCD chunk swizzle: all gridDim.x N-tiles of one (e,m) land on one
// XCD contiguously (A-panel L2 reuse). Bijective because gridDim.z==8 makes
// total % (8*G) == 0 with G = gridDim.x.  [T1/m204]
__device__ inline void xcd_swizzle(int& e, int& m, int& n) {
  int gx = gridDim.x, gy = gridDim.y;
  int f = (blockIdx.z * gy + blockIdx.y) * gx + blockIdx.x;
  int xcd = f & 7, idx = f >> 3;
  int chunk = idx / gx, pos = idx - chunk * gx;
  int logical = chunk * (8 * gx) + xcd * gx + pos;
  int mn = gy * gx;
  e = logical / mn;
  int rem = logical - e * mn;
  m = rem / gx;
  n = rem - m * gx;
}

// ------- fp32 [E][K][N] -> fp16 [E][N][K] transpose-convert (64x64 tiles) -------
// float4 loads, LDS [64][65] (2-way bank aliasing only = free), half2 stores
// coalesced along K.
__global__ __launch_bounds__(256)
void cvtT_kernel(const float* __restrict__ in, __half* __restrict__ out,
                 int K, int N) {
  __shared__ float tile[64][65];
  int e = blockIdx.z;
  const float* inp = in + (size_t)e * K * N + (size_t)(blockIdx.y * 64) * N + blockIdx.x * 64;
  __half* outp = out + (size_t)e * K * N + (size_t)(blockIdx.x * 64) * K + blockIdx.y * 64;
  int s = threadIdx.x;
  int tx = s & 15, r0 = s >> 4;           // tx: float4 col group, r0: row 0..15
#pragma unroll
  for (int i = 0; i < 4; ++i) {
    int k = r0 + i * 16;
    float4 v = *(const float4*)&inp[(size_t)k * N + tx * 4];
    tile[k][tx * 4 + 0] = v.x;
    tile[k][tx * 4 + 1] = v.y;
    tile[k][tx * 4 + 2] = v.z;
    tile[k][tx * 4 + 3] = v.w;
  }
  __syncthreads();
  int kp = s & 31;                         // k-pair 0..31
#pragma unroll
  for (int i = 0; i < 8; ++i) {
    int n = (s >> 5) + i * 8;
    __half2 h = __floats2half2_rn(tile[2 * kp][n], tile[2 * kp + 1][n]);
    *(__half2*)&outp[(size_t)n * K + kp * 2] = h;
  }
}

// ------- router: fp32 logits, top-2, softmax; also emits xh (fp16 copy of x) -------
__global__ __launch_bounds__(256)
void router_kernel(const float* __restrict__ x, const float* __restrict__ Wr,
                   const float* __restrict__ br, int* __restrict__ counts,
                   int* __restrict__ sel, float* __restrict__ wTok,
                   __half* __restrict__ xh) {
  __shared__ float wr_s[EE * DD];  // transposed [e][d], 24KB
  for (int i = threadIdx.x; i < EE * DD; i += 256) {
    int d = i >> 3, e = i & 7;
    wr_s[e * DD + d] = Wr[i];
  }
  __syncthreads();
  int wid = threadIdx.x >> 6, lane = threadIdx.x & 63;
  int t = blockIdx.x * 4 + wid;
  const float* xt = x + (size_t)t * DD;
  float acc[EE];
#pragma unroll
  for (int e = 0; e < EE; ++e) acc[e] = 0.f;
  for (int d = lane; d < DD; d += 64) {
    float xv = xt[d];
#pragma unroll
    for (int e = 0; e < EE; ++e) acc[e] += xv * wr_s[e * DD + d];
  }
#pragma unroll
  for (int off = 32; off > 0; off >>= 1)
#pragma unroll
    for (int e = 0; e < EE; ++e) acc[e] += __shfl_xor(acc[e], off);
  if (lane == 0) {
    float v[EE];
#pragma unroll
    for (int e = 0; e < EE; ++e) v[e] = acc[e] + br[e];
    int i0 = 0;
#pragma unroll
    for (int e = 1; e < EE; ++e) if (v[e] > v[i0]) i0 = e;
    int i1 = (i0 == 0) ? 1 : 0;
#pragma unroll
    for (int e = 0; e < EE; ++e) if (e != i0 && v[e] > v[i1] && e != i1) { if (v[e] > v[i1]) i1 = e; }
    float e1 = __expf(v[i1] - v[i0]);
    float s = 1.f / (1.f + e1);
    sel[2 * t] = i0; sel[2 * t + 1] = i1;
    wTok[2 * t] = s; wTok[2 * t + 1] = e1 * s;
    atomicAdd(&counts[i0], 1);
    atomicAdd(&counts[i1], 1);
  }
  // fused x -> fp16 conversion for this wave's token row (replaces cvt_kernel)
  const float4* xr = (const float4*)xt;
  uint2* xo = (uint2*)(xh + (size_t)t * DD);
#pragma unroll
  for (int j = 0; j < 3; ++j) {
    float4 v = xr[lane + j * 64];
    __half2 a = __floats2half2_rn(v.x, v.y);
    __half2 b = __floats2half2_rn(v.z, v.w);
    uint2 p;
    p.x = *(const unsigned int*)&a;
    p.y = *(const unsigned int*)&b;
    xo[lane + j * 64] = p;
  }
}

// ---------------- offsets (prefix over 8) ----------------
__global__ void offsets_kernel(const int* __restrict__ counts, int* __restrict__ offsets,
                               int* __restrict__ cursors) {
  if (threadIdx.x == 0) {
    int o = 0;
    for (int e = 0; e < EE; ++e) { offsets[e] = o; cursors[e] = o; o += counts[e]; }
  }
}

// ---------------- scatter token->slot ----------------
__global__ void scatter_kernel(const int* __restrict__ sel, int* __restrict__ cursors,
                               int* __restrict__ idxList, int* __restrict__ posTok) {
  int t = blockIdx.x * 256 + threadIdx.x;
  if (t < TK) {
#pragma unroll
    for (int k = 0; k < 2; ++k) {
      int e = sel[2 * t + k];
      int p = atomicAdd(&cursors[e], 1);
      idxList[p] = t;
      posTok[2 * t + k] = p;
    }
  }
}

// ---------------- FFN GEMM (8-phase 256x256, all stages) ----------------
// R2/R5-verified schedule: 8 waves (2Mx4N), BK=64, dbuf, quarter-granular
// staging, counted vmcnt(6), setprio around MFMA, XOR-swizzled LDS.
template<int KD, int ND, bool GATHER, bool GELU>
__global__ __launch_bounds__(512, 1)
void ffn_gemm8(const __half* __restrict__ A, const __half* __restrict__ Wt,
               const float* __restrict__ Bias, __half* __restrict__ Out,
               const int* __restrict__ counts, const int* __restrict__ offsets,
               const int* __restrict__ idxList) {
  constexpr int NT = KD / 64;
  int e, mblk, nblk;
  xcd_swizzle(e, mblk, nblk);
  const int cnt = counts[e];
  const int m0 = mblk * 256;
  if (cnt == 0 || m0 >= cnt) return;
  const int off = offsets[e];
  const int n0 = nblk * 256;
  const __half* We = Wt + (size_t)e * KD * ND;
  const float* be = Bias + (size_t)e * ND;

  __shared__ __align__(16) __half As[2][256 * 64];
  __shared__ __align__(16) __half Bs[2][256 * 64];

  const int tid = threadIdx.x;
  const int srow = tid >> 3;                 // 0..63 row within quarter
  const int swz = ((tid & 7) ^ (srow & 7)) << 3;

  const __half* aptr[4];
  const __half* bptr[4];
#pragma unroll
  for (int q = 0; q < 4; ++q) {
    int gr = m0 + q * 64 + srow;
    if (gr > cnt - 1) gr = cnt - 1;          // clamp tail (writes guarded)
    size_t arow = GATHER ? (size_t)idxList[off + gr] : (size_t)(off + gr);
    aptr[q] = A + arow * KD + swz;
    bptr[q] = We + (size_t)(n0 + q * 64 + srow) * KD + swz;
  }

#define STAGE_A(BUF, Q, TS) GLOAD_LDS16(aptr[Q] + (TS) * 64, &As[BUF][(Q) * 4096 + tid * 8])
#define STAGE_B(BUF, Q, TS) GLOAD_LDS16(bptr[Q] + (TS) * 64, &Bs[BUF][(Q) * 4096 + tid * 8])

  const int lane = tid & 63, wv = tid >> 6;
  const int wr = wv >> 2, wc = wv & 3;       // 2 x 4 wave grid
  const int lrow = lane & 15, lg = lane >> 4;
  const int rowa = wr * 128 + lrow;
  const int rowb = wc * 64 + lrow;
  int aoff[2], boff[2];
#pragma unroll
  for (int kk = 0; kk < 2; ++kk) {
    aoff[kk] = rowa * 64 + (((kk * 4 + lg) ^ (rowa & 7)) << 3);
    boff[kk] = rowb * 64 + (((kk * 4 + lg) ^ (rowb & 7)) << 3);
  }

  floatx4 acc[8][4];
#pragma unroll
  for (int mi = 0; mi < 8; ++mi)
#pragma unroll
    for (int ni = 0; ni < 4; ++ni) acc[mi][ni] = (floatx4){0.f, 0.f, 0.f, 0.f};

  // ---- prologue: tile0 fully, tile1 minus B-q2,q3 (staged at t0.a) ----
#pragma unroll
  for (int q = 0; q < 4; ++q) STAGE_A(0, q, 0);
#pragma unroll
  for (int q = 0; q < 4; ++q) STAGE_B(0, q, 0);
#pragma unroll
  for (int q = 0; q < 4; ++q) STAGE_A(1, q, 1);
  STAGE_B(1, 0, 1);
  STAGE_B(1, 1, 1);
  asm volatile("s_waitcnt vmcnt(6)" ::: "memory");   // tile0's 8 quarters landed
  __builtin_amdgcn_s_barrier();

#define BAR() __builtin_amdgcn_s_barrier()
#define WLG() do { asm volatile("s_waitcnt lgkmcnt(0)" ::: "memory"); \
                   __builtin_amdgcn_sched_barrier(0); } while (0)
#define P1() __builtin_amdgcn_s_setprio(1)
#define P0() __builtin_amdgcn_s_setprio(0)
#define MMQ(AF, BF, MB, NB) \
  _Pragma("unroll") for (int kk = 0; kk < 2; ++kk) \
  _Pragma("unroll") for (int mi = 0; mi < 4; ++mi) \
  _Pragma("unroll") for (int ni = 0; ni < 2; ++ni) \
    acc[(MB) + mi][(NB) + ni] = __builtin_amdgcn_mfma_f32_16x16x32_f16( \
        AF[mi][kk], BF[ni][kk], acc[(MB) + mi][(NB) + ni], 0, 0, 0);

#define PHASES(CUR, NXT, TT) { \
  const __half* Ac = &As[CUR][0]; \
  const __half* Bc = &Bs[CUR][0]; \
  half8 af[4][2], bf0[2][2], bf1[2][2]; \
  _Pragma("unroll") for (int mi = 0; mi < 4; ++mi) \
  _Pragma("unroll") for (int kk = 0; kk < 2; ++kk) \
    af[mi][kk] = *(const half8*)&Ac[aoff[kk] + mi * 1024]; \
  _Pragma("unroll") for (int ni = 0; ni < 2; ++ni) \
  _Pragma("unroll") for (int kk = 0; kk < 2; ++kk) \
    bf0[ni][kk] = *(const half8*)&Bc[boff[kk] + ni * 1024]; \
  if ((TT) + 1 < NT) { STAGE_B(NXT, 2, (TT) + 1); STAGE_B(NXT, 3, (TT) + 1); } \
  BAR(); WLG(); P1(); MMQ(af, bf0, 0, 0); P0(); BAR(); \
  _Pragma("unroll") for (int ni = 0; ni < 2; ++ni) \
  _Pragma("unroll") for (int kk = 0; kk < 2; ++kk) \
    bf1[ni][kk] = *(const half8*)&Bc[boff[kk] + (ni + 2) * 1024]; \
  if ((TT) + 2 < NT) { STAGE_A(CUR, 0, (TT) + 2); STAGE_A(CUR, 2, (TT) + 2); } \
  BAR(); WLG(); P1(); MMQ(af, bf1, 0, 2); P0(); BAR(); \
  _Pragma("unroll") for (int mi = 0; mi < 4; ++mi) \
  _Pragma("unroll") for (int kk = 0; kk < 2; ++kk) \
    af[mi][kk] = *(const half8*)&Ac[aoff[kk] + (mi + 4) * 1024]; \
  if ((TT) + 2 < NT) { STAGE_B(CUR, 0, (TT) + 2); STAGE_B(CUR, 1, (TT) + 2); } \
  BAR(); WLG(); P1(); MMQ(af, bf0, 4, 0); P0(); BAR(); \
  if ((TT) + 2 < NT) { STAGE_A(CUR, 1, (TT) + 2); STAGE_A(CUR, 3, (TT) + 2); } \
  BAR(); P1(); MMQ(af, bf1, 4, 2); P0(); \
  if ((TT) + 2 < NT) { asm volatile("s_waitcnt vmcnt(6)" ::: "memory"); } \
  else              { asm volatile("s_waitcnt vmcnt(0)" ::: "memory"); } \
  BAR(); }

  for (int t = 0; t < NT; t += 2) {
    PHASES(0, 1, t)
    PHASES(1, 0, t + 1)
  }

  // ---- epilogue: bias + optional erf-GELU, guarded rows ----
  const int crow = m0 + wr * 128 + lg * 4;
  const int ccol = n0 + wc * 64 + lrow;
  float bv[4];
#pragma unroll
  for (int ni = 0; ni < 4; ++ni) bv[ni] = be[ccol + ni * 16];
#pragma unroll
  for (int mi = 0; mi < 8; ++mi) {
#pragma unroll
    for (int j = 0; j < 4; ++j) {
      int r = crow + mi * 16 + j;
      if (r < cnt) {
#pragma unroll
        for (int ni = 0; ni < 4; ++ni) {
          float v = acc[mi][ni][j] + bv[ni];
          if (GELU) v = 0.5f * v * (1.f + erff(v * 0.70710678118654752f));
          Out[(size_t)(off + r) * ND + ccol + ni * 16] = __float2half(v);
        }
      }
    }
  }
#undef STAGE_A
#undef STAGE_B
#undef BAR
#undef WLG
#undef P1
#undef P0
#undef MMQ
#undef PHASES
}

// ---------------- combine: out[t] = w0*yc[p0] + w1*yc[p1] ----------------
__global__ void combine_kernel(const __half* __restrict__ yc, const float* __restrict__ wTok,
                               const int* __restrict__ posTok, float* __restrict__ out) {
  int t = blockIdx.x;
  int d = threadIdx.x * 4;
  if (d >= DD) return;
  float w0 = wTok[2 * t], w1 = wTok[2 * t + 1];
  const __half2* a = (const __half2*)(yc + (size_t)posTok[2 * t] * DD + d);
  const __half2* b = (const __half2*)(yc + (size_t)posTok[2 * t + 1] * DD + d);
  float2 a0 = __half22float2(a[0]), a1 = __half22float2(a[1]);
  float2 b0 = __half22float2(b[0]), b1 = __half22float2(b[1]);
  float4 r;
  r.x = w0 * a0.x + w1 * b0.x;
  r.y = w0 * a0.y + w1 * b0.y;
  r.z = w0 * a1.x + w1 * b1.x;
  r.w = w0 * a1.y + w1 * b1.y;
  *(float4*)(out + (size_t)t * DD + d) = r;
}

extern "C" void kernel_launch(void* const* d_in, const int* in_sizes, int n_in,
                              void* d_out, int out_size, void* d_ws, size_t ws_size,
                              hipStream_t stream) {
  const float* x  = (const float*)d_in[0];
  const float* Wr = (const float*)d_in[1];
  const float* br = (const float*)d_in[2];
  const float* W1 = (const float*)d_in[3];
  const float* b1 = (const float*)d_in[4];
  const float* W2 = (const float*)d_in[5];
  const float* b2 = (const float*)d_in[6];
  const float* W3 = (const float*)d_in[7];
  const float* b3 = (const float*)d_in[8];
  float* out = (float*)d_out;

  char* ws = (char*)d_ws;
  size_t o = 0;
  auto alloc = [&](size_t bytes) {
    char* p = ws + o;
    o += (bytes + 255) & ~(size_t)255;
    return p;
  };
  __half* xh   = (__half*)alloc((size_t)TK * DD * 2);
  __half* w1t  = (__half*)alloc((size_t)EE * DD * II * 2);
  __half* w2t  = (__half*)alloc((size_t)EE * II * HH * 2);
  __half* w3t  = (__half*)alloc((size_t)EE * HH * DD * 2);
  __half* h1   = (__half*)alloc((size_t)2 * TK * II * 2);
  __half* h2   = (__half*)alloc((size_t)2 * TK * HH * 2);
  __half* yc   = (__half*)alloc((size_t)2 * TK * DD * 2);
  int*   idxL  = (int*)alloc(2 * TK * 4);
  int*   sel   = (int*)alloc(2 * TK * 4);
  float* wTok  = (float*)alloc(2 * TK * 4);
  int*   posT  = (int*)alloc(2 * TK * 4);
  int*   counts  = (int*)alloc(256);
  int*   offsets = (int*)alloc(256);
  int*   cursors = (int*)alloc(256);
  if (o > ws_size) return;  // workspace too small -> loud absmax failure

  hipMemsetAsync(counts, 0, 256, stream);

  cvtT_kernel<<<dim3(II / 64, DD / 64, EE), 256, 0, stream>>>(W1, w1t, DD, II);
  cvtT_kernel<<<dim3(HH / 64, II / 64, EE), 256, 0, stream>>>(W2, w2t, II, HH);
  cvtT_kernel<<<dim3(DD / 64, HH / 64, EE), 256, 0, stream>>>(W3, w3t, HH, DD);
  router_kernel<<<TK / 4, 256, 0, stream>>>(x, Wr, br, counts, sel, wTok, xh);
  offsets_kernel<<<1, 64, 0, stream>>>(counts, offsets, cursors);
  scatter_kernel<<<TK / 256, 256, 0, stream>>>(sel, cursors, idxL, posT);

  ffn_gemm8<DD, II, true,  true ><<<dim3(II / 256, 64, EE), 512, 0, stream>>>(
      xh, w1t, b1, h1, counts, offsets, idxL);
  ffn_gemm8<II, HH, false, true ><<<dim3(HH / 256, 64, EE), 512, 0, stream>>>(
      h1, w2t, b2, h2, counts, offsets, idxL);
  ffn_gemm8<HH, DD, false, false><<<dim3(DD / 256, 64, EE), 512, 0, stream>>>(
      h2, w3t, b3, yc, counts, offsets, idxL);

  combine_kernel<<<TK, 192, 0, stream>>>(yc, wTok, posT, out);
}